// Round 1
// baseline (468.846 us; speedup 1.0000x reference)
//
#include <hip/hip_runtime.h>
#include <math.h>

#define K_TOP 512

struct LvlC {
  int H, lgH, HH, lgHH;
  float fs, wsc, hsc, wex, hex, pwlo, pwhi, phlo, phhi, minwh, maxwh;
};

__device__ const LvlC LVL[4] = {
  {128, 7, 16384, 14, 0.25f,    0.8f, 1.0f, 0.2f, 0.4f, 0.008f, 0.054f, 0.008f, 0.072f, 0.005f, 0.12f},
  { 64, 6,  4096, 12, 0.125f,   0.9f, 1.2f, 0.3f, 0.6f, 0.016f, 0.072f, 0.016f, 0.096f, 0.01f,  0.16f},
  { 32, 5,  1024, 10, 0.0625f,  1.0f, 1.4f, 0.4f, 0.8f, 0.024f, 0.09f,  0.024f, 0.12f,  0.015f, 0.2f },
  { 16, 4,   256,  8, 0.03125f, 1.1f, 1.6f, 0.5f, 1.0f, 0.032f, 0.108f, 0.032f, 0.144f, 0.02f,  0.24f},
};

// Decode one anchor's box (matches reference decode_level exactly, f32, no FMA contraction)
__device__ __forceinline__ void decode_box(const LvlC& L, const float* __restrict__ boxp,
                                           const float* __restrict__ ancp,
                                           int b, int idx, float imgf,
                                           float& x0, float& y0, float& x1, float& y1)
{
#pragma clang fp contract(off)
  int a   = idx >> L.lgHH;
  int rem = idx & (L.HH - 1);
  const float* bp = boxp + (size_t)((b * 3 + a) * 4) * L.HH + rem;
  float d0 = bp[0], d1 = bp[L.HH], d2 = bp[2 * L.HH], d3 = bp[3 * L.HH];
  const float* ap = ancp + (size_t)idx * 4;
  float a0 = ap[0], a1 = ap[1], a2 = ap[2], a3 = ap[3];
  float aw  = (a2 - a0) / imgf;
  float ah  = (a3 - a1) / imgf;
  float acx = (a0 + a2) * 0.5f / imgf;
  float acy = (a1 + a3) * 0.5f / imgf;
  float dx = fminf(fmaxf(d0 * 0.2f, -1.f), 1.f) * L.fs * aw;
  float dy = fminf(fmaxf(d1 * 0.2f, -1.f), 1.f) * L.fs * ah;
  float cx = fminf(fmaxf(acx + dx, 0.f), 1.f);
  float cy = fminf(fmaxf(acy + dy, 0.f), 1.f);
  float dw = fminf(fmaxf(d2 * 0.2f, -2.f), 2.f);
  float dh = fminf(fmaxf(d3 * 0.2f, -2.f), 2.f);
  float pw = fminf(fmaxf(aw * L.wsc * expf(dw * L.wex), L.pwlo), L.pwhi);
  float ph = fminf(fmaxf(ah * L.hsc * expf(dh * L.hex), L.phlo), L.phhi);
  x0 = fminf(fmaxf(cx - 0.5f * pw, 0.f), 1.f);
  y0 = fminf(fmaxf(cy - 0.5f * ph, 0.f), 1.f);
  x1 = fminf(fmaxf(cx + 0.5f * pw, 0.f), 1.f);
  y1 = fminf(fmaxf(cy + 0.5f * ph, 0.f), 1.f);
}

// ---------------- Kernel 1: decode all anchors -> 64-bit sort keys ----------------
// key = [ ~flip(sort_key) :32 | idx:16 | label:8 | valid:1 ]  (ascending u64 == top_k order)
__global__ __launch_bounds__(256) void decode_kernel(
    const float* __restrict__ cls0, const float* __restrict__ box0, const float* __restrict__ anc0,
    const float* __restrict__ cls1, const float* __restrict__ box1, const float* __restrict__ anc1,
    const float* __restrict__ cls2, const float* __restrict__ box2, const float* __restrict__ anc2,
    const float* __restrict__ cls3, const float* __restrict__ box3, const float* __restrict__ anc3,
    const int* __restrict__ imgp, unsigned long long* __restrict__ keys)
{
  int blk = blockIdx.x;
  int b   = blk / 255;           // 255 blocks per batch (65280/256)
  int rb  = blk - b * 255;
  int l, iblk, base;
  if (rb < 192)      { l = 0; iblk = rb;       base = 0;     }
  else if (rb < 240) { l = 1; iblk = rb - 192; base = 49152; }
  else if (rb < 252) { l = 2; iblk = rb - 240; base = 61440; }
  else               { l = 3; iblk = rb - 252; base = 64512; }
  int i = iblk * 256 + (int)threadIdx.x;

  const float *cls, *boxp, *ancp;
  switch (l) {
    case 0:  cls = cls0; boxp = box0; ancp = anc0; break;
    case 1:  cls = cls1; boxp = box1; ancp = anc1; break;
    case 2:  cls = cls2; boxp = box2; ancp = anc2; break;
    default: cls = cls3; boxp = box3; ancp = anc3; break;
  }
  LvlC L = LVL[l];
  float imgf = (float)(*imgp);

  int a   = i >> L.lgHH;
  int rem = i & (L.HH - 1);
  const float* cp = cls + (size_t)((b * 3 + a) * 3) * L.HH + rem;
  float c0 = cp[0], c1 = cp[L.HH], c2 = cp[2 * L.HH];
  float m = c0; int mc = 0;
  if (c1 > m) { m = c1; mc = 1; }
  if (c2 > m) { m = c2; mc = 2; }
  float ms = 1.f / (1.f + expf(-m));   // max of sigmoids == sigmoid of max logit

  float x0, y0, x1, y1;
  decode_box(L, boxp, ancp, b, i, imgf, x0, y0, x1, y1);
  float w = x1 - x0, h = y1 - y0;
  bool valid = (ms > 0.15f) && (w > L.minwh) && (h > L.minwh) && (w < L.maxwh) && (h < L.maxwh);

  float sk = valid ? ms : -1.0f;
  unsigned u = __float_as_uint(sk);
  unsigned ascu  = (u & 0x80000000u) ? ~u : (u | 0x80000000u); // ascending-float -> ascending-uint
  unsigned descu = ~ascu;                                      // descending-float -> ascending-uint
  unsigned long long key = ((unsigned long long)descu << 32)
                         | ((unsigned long long)(unsigned)i << 16)
                         | ((unsigned)mc << 8) | (valid ? 1u : 0u);
  keys[(size_t)b * 65280 + base + i] = key;
}

// ---------------- Kernel 2: per-segment exact top-512 (radix select + bitonic sort) ----------------
__global__ __launch_bounds__(512) void select_kernel(const unsigned long long* __restrict__ keys,
                                                     unsigned long long* __restrict__ sel)
{
  __shared__ unsigned hist[256];
  __shared__ unsigned long long skey[K_TOP];
  __shared__ unsigned long long sh_prefix;
  __shared__ unsigned sh_below, sh_cnt;

  int seg = blockIdx.x;
  int b = seg >> 2, l = seg & 3;
  const int nArr[4]    = {49152, 12288, 3072, 768};
  const int baseArr[4] = {0, 49152, 61440, 64512};
  int N = nArr[l];
  const unsigned long long* kp = keys + (size_t)b * 65280 + baseArr[l];
  int tid = (int)threadIdx.x;
  const int nt = 512;

  if (tid == 0) { sh_prefix = 0ull; sh_below = 0u; sh_cnt = 0u; }

  for (int r = 0; r < 6; ++r) {           // top 48 bits are unique per segment
    for (int v = tid; v < 256; v += nt) hist[v] = 0u;
    __syncthreads();
    unsigned long long pref = sh_prefix;
    int shift = 56 - 8 * r;
    unsigned long long hiMask = (r == 0) ? 0ull : (~0ull << (64 - 8 * r));
    for (int t = tid; t < N; t += nt) {
      unsigned long long k = kp[t];
      if ((k & hiMask) == (pref & hiMask)) {
        unsigned d = (unsigned)((k >> shift) & 0xFF);
        atomicAdd(&hist[d], 1u);
      }
    }
    __syncthreads();
    if (tid == 0) {
      unsigned c = sh_below; int v = 0;
      for (; v < 255; ++v) { if (c + hist[v] >= K_TOP) break; c += hist[v]; }
      sh_below = c;
      sh_prefix = sh_prefix | ((unsigned long long)v << shift);
    }
    __syncthreads();
  }
  unsigned long long kth = sh_prefix | 0xFFFFull;

  // compact: exactly 512 keys satisfy key <= kth (top-48 bits unique)
  for (int t = tid; t < N; t += nt) {
    unsigned long long k = kp[t];
    if (k <= kth) { unsigned p = atomicAdd(&sh_cnt, 1u); skey[p] = k; }
  }
  __syncthreads();

  // bitonic sort 512 ascending
  for (int kk = 2; kk <= K_TOP; kk <<= 1) {
    for (int j = kk >> 1; j > 0; j >>= 1) {
      int i1 = tid;
      if (i1 < K_TOP) {
        int ixj = i1 ^ j;
        if (ixj > i1) {
          bool up = ((i1 & kk) == 0);
          unsigned long long A = skey[i1], B = skey[ixj];
          if ((A > B) == up) { skey[i1] = B; skey[ixj] = A; }
        }
      }
      __syncthreads();
    }
  }
  for (int t = tid; t < K_TOP; t += nt) sel[(size_t)seg * K_TOP + t] = skey[t];
}

// ---------------- Kernel 3: one wave per segment — re-decode, greedy NMS, write outputs ----------------
__global__ __launch_bounds__(64) void nms_kernel(
    const unsigned long long* __restrict__ sel,
    const float* __restrict__ box0, const float* __restrict__ anc0,
    const float* __restrict__ box1, const float* __restrict__ anc1,
    const float* __restrict__ box2, const float* __restrict__ anc2,
    const float* __restrict__ box3, const float* __restrict__ anc3,
    const int* __restrict__ imgp, float* __restrict__ out)
{
  int seg = blockIdx.x;
  int b = seg >> 2, l = seg & 3;
  int lane = (int)threadIdx.x;
  const float *boxp, *ancp;
  switch (l) {
    case 0:  boxp = box0; ancp = anc0; break;
    case 1:  boxp = box1; ancp = anc1; break;
    case 2:  boxp = box2; ancp = anc2; break;
    default: boxp = box3; ancp = anc3; break;
  }
  LvlC L = LVL[l];
  float imgf = (float)(*imgp);

  // lane holds boxes i = r*64 + lane, r = 0..7
  float bx0[8], by0[8], bx1[8], by1[8], sc[8], ar[8], ov[8];
  int lb[8]; bool vd[8]; bool kp[8];

#pragma unroll
  for (int r = 0; r < 8; ++r) {
    unsigned long long key = sel[(size_t)seg * K_TOP + r * 64 + lane];
    vd[r] = (key & 1ull) != 0ull;
    lb[r] = (int)((key >> 8) & 0xFFull);
    int idx = (int)((key >> 16) & 0xFFFFull);
    unsigned descu = (unsigned)(key >> 32);
    unsigned ascu  = ~descu;
    unsigned u = (ascu & 0x80000000u) ? (ascu & 0x7FFFFFFFu) : ~ascu;
    sc[r] = __uint_as_float(u);          // == sort_key; == ms for valid entries
    decode_box(L, boxp, ancp, b, idx, imgf, bx0[r], by0[r], bx1[r], by1[r]);
    ar[r] = (bx1[r] - bx0[r]) * (by1[r] - by0[r]);
    ov[r] = 0.f;
    kp[r] = false;
  }

  // greedy NMS: 512 sequential steps, in-wave broadcasts, no barriers
#pragma unroll
  for (int r = 0; r < 8; ++r) {
    for (int inner = 0; inner < 64; ++inner) {
      int myDec = (vd[r] && (ov[r] <= 0.5f)) ? 1 : 0;
      int dec = __shfl(myDec, inner);          // owner lane's decision for box i = r*64+inner
      if (lane == inner) kp[r] = (dec != 0);
      if (dec) {
        float p0 = __shfl(bx0[r], inner);
        float p1 = __shfl(by0[r], inner);
        float p2 = __shfl(bx1[r], inner);
        float p3 = __shfl(by1[r], inner);
        float areaB = (p2 - p0) * (p3 - p1);
#pragma unroll
        for (int r2 = r; r2 < 8; ++r2) {
          float ltx = fmaxf(bx0[r2], p0), lty = fmaxf(by0[r2], p1);
          float rbx = fminf(bx1[r2], p2), rby = fminf(by1[r2], p3);
          float ww = fmaxf(rbx - ltx, 0.f), hh = fmaxf(rby - lty, 0.f);
          float inter = ww * hh;
          float iou = inter / (ar[r2] + areaB - inter + 1e-9f);
          if (r2 > r || lane > inner) ov[r2] = fmaxf(ov[r2], iou);
        }
      }
    }
  }

  // epilogue: boxes | scores | labels+1 | keep (zeros where not kept)
#pragma unroll
  for (int r = 0; r < 8; ++r) {
    int k = r * 64 + lane;
    size_t o = (size_t)seg * K_TOP + k;
    bool keep = kp[r];
    float4 ob;
    ob.x = keep ? bx0[r] : 0.f;
    ob.y = keep ? by0[r] : 0.f;
    ob.z = keep ? bx1[r] : 0.f;
    ob.w = keep ? by1[r] : 0.f;
    reinterpret_cast<float4*>(out)[o] = ob;                 // boxes:  [0,      32768)
    out[32768 + o] = keep ? sc[r] : 0.f;                    // scores: [32768,  40960)
    out[40960 + o] = keep ? (float)(lb[r] + 1) : 0.f;       // labels: [40960,  49152)
    out[49152 + o] = keep ? 1.f : 0.f;                      // keep:   [49152,  57344)
  }
}

extern "C" void kernel_launch(void* const* d_in, const int* in_sizes, int n_in,
                              void* d_out, int out_size, void* d_ws, size_t ws_size,
                              hipStream_t stream)
{
  const float* cls0 = (const float*)d_in[0];
  const float* box0 = (const float*)d_in[1];
  const float* anc0 = (const float*)d_in[2];
  const float* cls1 = (const float*)d_in[3];
  const float* box1 = (const float*)d_in[4];
  const float* anc1 = (const float*)d_in[5];
  const float* cls2 = (const float*)d_in[6];
  const float* box2 = (const float*)d_in[7];
  const float* anc2 = (const float*)d_in[8];
  const float* cls3 = (const float*)d_in[9];
  const float* box3 = (const float*)d_in[10];
  const float* anc3 = (const float*)d_in[11];
  const int*   imgp = (const int*)d_in[12];

  unsigned long long* keys = (unsigned long long*)d_ws;   // 261120 * 8B = 2,088,960 B
  unsigned long long* sel  = keys + 261120;               // 16*512*8B = 65,536 B
  float* out = (float*)d_out;

  decode_kernel<<<1020, 256, 0, stream>>>(cls0, box0, anc0, cls1, box1, anc1,
                                          cls2, box2, anc2, cls3, box3, anc3,
                                          imgp, keys);
  select_kernel<<<16, 512, 0, stream>>>(keys, sel);
  nms_kernel<<<16, 64, 0, stream>>>(sel, box0, anc0, box1, anc1,
                                    box2, anc2, box3, anc3, imgp, out);
}

// Round 2
// 171.741 us; speedup vs baseline: 2.7300x; 2.7300x over previous
//
#include <hip/hip_runtime.h>
#include <math.h>

#define K_TOP 512
#define SBUF_CAP 3072

struct LvlC {
  int H, lgH, HH, lgHH;
  float fs, wsc, hsc, wex, hex, pwlo, pwhi, phlo, phhi, minwh, maxwh;
};

__device__ const LvlC LVL[4] = {
  {128, 7, 16384, 14, 0.25f,    0.8f, 1.0f, 0.2f, 0.4f, 0.008f, 0.054f, 0.008f, 0.072f, 0.005f, 0.12f},
  { 64, 6,  4096, 12, 0.125f,   0.9f, 1.2f, 0.3f, 0.6f, 0.016f, 0.072f, 0.016f, 0.096f, 0.01f,  0.16f},
  { 32, 5,  1024, 10, 0.0625f,  1.0f, 1.4f, 0.4f, 0.8f, 0.024f, 0.09f,  0.024f, 0.12f,  0.015f, 0.2f },
  { 16, 4,   256,  8, 0.03125f, 1.1f, 1.6f, 0.5f, 1.0f, 0.032f, 0.108f, 0.032f, 0.144f, 0.02f,  0.24f},
};

// Decode one anchor's box (matches reference decode_level exactly, f32, no FMA contraction)
__device__ __forceinline__ void decode_box(const LvlC& L, const float* __restrict__ boxp,
                                           const float* __restrict__ ancp,
                                           int b, int idx, float imgf,
                                           float& x0, float& y0, float& x1, float& y1)
{
#pragma clang fp contract(off)
  int a   = idx >> L.lgHH;
  int rem = idx & (L.HH - 1);
  const float* bp = boxp + (size_t)((b * 3 + a) * 4) * L.HH + rem;
  float d0 = bp[0], d1 = bp[L.HH], d2 = bp[2 * L.HH], d3 = bp[3 * L.HH];
  const float* ap = ancp + (size_t)idx * 4;
  float a0 = ap[0], a1 = ap[1], a2 = ap[2], a3 = ap[3];
  float aw  = (a2 - a0) / imgf;
  float ah  = (a3 - a1) / imgf;
  float acx = (a0 + a2) * 0.5f / imgf;
  float acy = (a1 + a3) * 0.5f / imgf;
  float dx = fminf(fmaxf(d0 * 0.2f, -1.f), 1.f) * L.fs * aw;
  float dy = fminf(fmaxf(d1 * 0.2f, -1.f), 1.f) * L.fs * ah;
  float cx = fminf(fmaxf(acx + dx, 0.f), 1.f);
  float cy = fminf(fmaxf(acy + dy, 0.f), 1.f);
  float dw = fminf(fmaxf(d2 * 0.2f, -2.f), 2.f);
  float dh = fminf(fmaxf(d3 * 0.2f, -2.f), 2.f);
  float pw = fminf(fmaxf(aw * L.wsc * expf(dw * L.wex), L.pwlo), L.pwhi);
  float ph = fminf(fmaxf(ah * L.hsc * expf(dh * L.hex), L.phlo), L.phhi);
  x0 = fminf(fmaxf(cx - 0.5f * pw, 0.f), 1.f);
  y0 = fminf(fmaxf(cy - 0.5f * ph, 0.f), 1.f);
  x1 = fminf(fmaxf(cx + 0.5f * pw, 0.f), 1.f);
  y1 = fminf(fmaxf(cy + 0.5f * ph, 0.f), 1.f);
}

// ---------------- Kernel 1: decode all anchors -> 64-bit sort keys + global byte0 hist ----------------
// key = [ ~flip(sort_key) :32 | idx:16 | label:8 | valid:1 ]  (ascending u64 == top_k order)
__global__ __launch_bounds__(256) void decode_kernel(
    const float* __restrict__ cls0, const float* __restrict__ box0, const float* __restrict__ anc0,
    const float* __restrict__ cls1, const float* __restrict__ box1, const float* __restrict__ anc1,
    const float* __restrict__ cls2, const float* __restrict__ box2, const float* __restrict__ anc2,
    const float* __restrict__ cls3, const float* __restrict__ box3, const float* __restrict__ anc3,
    const int* __restrict__ imgp, unsigned long long* __restrict__ keys,
    unsigned* __restrict__ ghist)
{
  __shared__ unsigned lhist[256];
  int tid = (int)threadIdx.x;
  lhist[tid] = 0u;

  int blk = blockIdx.x;
  int b   = blk / 255;           // 255 blocks per batch (65280/256)
  int rb  = blk - b * 255;
  int l, iblk, base;
  if (rb < 192)      { l = 0; iblk = rb;       base = 0;     }
  else if (rb < 240) { l = 1; iblk = rb - 192; base = 49152; }
  else if (rb < 252) { l = 2; iblk = rb - 240; base = 61440; }
  else               { l = 3; iblk = rb - 252; base = 64512; }
  int i = iblk * 256 + tid;

  const float *cls, *boxp, *ancp;
  switch (l) {
    case 0:  cls = cls0; boxp = box0; ancp = anc0; break;
    case 1:  cls = cls1; boxp = box1; ancp = anc1; break;
    case 2:  cls = cls2; boxp = box2; ancp = anc2; break;
    default: cls = cls3; boxp = box3; ancp = anc3; break;
  }
  LvlC L = LVL[l];
  float imgf = (float)(*imgp);

  int a   = i >> L.lgHH;
  int rem = i & (L.HH - 1);
  const float* cp = cls + (size_t)((b * 3 + a) * 3) * L.HH + rem;
  float c0 = cp[0], c1 = cp[L.HH], c2 = cp[2 * L.HH];
  float m = c0; int mc = 0;
  if (c1 > m) { m = c1; mc = 1; }
  if (c2 > m) { m = c2; mc = 2; }
  float ms = 1.f / (1.f + expf(-m));   // max of sigmoids == sigmoid of max logit

  float x0, y0, x1, y1;
  decode_box(L, boxp, ancp, b, i, imgf, x0, y0, x1, y1);
  float w = x1 - x0, h = y1 - y0;
  bool valid = (ms > 0.15f) && (w > L.minwh) && (h > L.minwh) && (w < L.maxwh) && (h < L.maxwh);

  float sk = valid ? ms : -1.0f;
  unsigned u = __float_as_uint(sk);
  unsigned ascu  = (u & 0x80000000u) ? ~u : (u | 0x80000000u); // ascending-float -> ascending-uint
  unsigned descu = ~ascu;                                      // descending-float -> ascending-uint
  unsigned long long key = ((unsigned long long)descu << 32)
                         | ((unsigned long long)(unsigned)i << 16)
                         | ((unsigned)mc << 8) | (valid ? 1u : 0u);
  keys[(size_t)b * 65280 + base + i] = key;

  __syncthreads();
  atomicAdd(&lhist[(unsigned)(key >> 56)], 1u);
  __syncthreads();
  unsigned c = lhist[tid];
  if (c) atomicAdd(&ghist[(b * 4 + l) * 256 + tid], c);
}

// ---------------- Kernel 2: per-segment exact top-512 + decode selected boxes ----------------
__global__ __launch_bounds__(1024) void select_kernel(
    const unsigned long long* __restrict__ keys,
    const unsigned* __restrict__ ghist,
    const float* __restrict__ box0, const float* __restrict__ anc0,
    const float* __restrict__ box1, const float* __restrict__ anc1,
    const float* __restrict__ box2, const float* __restrict__ anc2,
    const float* __restrict__ box3, const float* __restrict__ anc3,
    const int* __restrict__ imgp,
    float* __restrict__ boxesWS, float* __restrict__ scoresWS,
    int* __restrict__ labelsWS, unsigned* __restrict__ validWS)
{
  __shared__ unsigned hist[16][256];
  __shared__ unsigned histT[256];
  __shared__ unsigned waveSum[4];
  __shared__ unsigned long long skey[K_TOP];
  __shared__ unsigned long long sbuf[SBUF_CAP];
  __shared__ unsigned long long sh_prefix;
  __shared__ unsigned sh_below, sh_cnt, sh_scnt;

  int seg = blockIdx.x;
  int b = seg >> 2, l = seg & 3;
  const int nArr[4]    = {49152, 12288, 3072, 768};
  const int baseArr[4] = {0, 49152, 61440, 64512};
  int N = nArr[l];
  const unsigned long long* kp = keys + (size_t)b * 65280 + baseArr[l];
  int tid = (int)threadIdx.x;
  const int nt = 1024;
  int wid = tid >> 6, lane = tid & 63;

  if (tid == 0) { sh_prefix = 0ull; sh_below = 0u; sh_cnt = 0u; sh_scnt = 0u; }
  __syncthreads();

  bool compacted = false;
  unsigned scnt = 0;

  for (int r = 0; r < 6; ++r) {
    unsigned long long pref = sh_prefix;
    unsigned below = sh_below;
    int shift = 56 - 8 * r;

    if (r == 0) {
      if (tid < 256) histT[tid] = ghist[seg * 256 + tid];
      __syncthreads();
    } else {
      for (int v2 = tid; v2 < 16 * 256; v2 += nt) ((unsigned*)hist)[v2] = 0u;
      __syncthreads();
      unsigned long long hiMask = ~0ull << (64 - 8 * r);
      int M = compacted ? (int)scnt : N;
      for (int t = tid; t < M; t += nt) {
        unsigned long long k = compacted ? sbuf[t] : kp[t];
        if ((k & hiMask) == (pref & hiMask))
          atomicAdd(&hist[wid][(unsigned)((k >> shift) & 0xFF)], 1u);
      }
      __syncthreads();
      if (tid < 256) {
        unsigned s = 0;
#pragma unroll
        for (int cpy = 0; cpy < 16; ++cpy) s += hist[cpy][tid];
        histT[tid] = s;
      }
      __syncthreads();
    }

    // block-parallel scan over 256 bins, pick winner digit
    unsigned v = (tid < 256) ? histT[tid] : 0u;
    unsigned incl = v;
    for (int off = 1; off < 64; off <<= 1) {
      unsigned n = __shfl_up(incl, off);
      if (lane >= off) incl += n;
    }
    if (lane == 63 && wid < 4) waveSum[wid] = incl;
    __syncthreads();
    if (tid < 256) {
      unsigned add = 0;
      for (int w2 = 0; w2 < wid; ++w2) add += waveSum[w2];
      unsigned inclT = incl + add;
      unsigned exclT = inclT - v;
      if (below + exclT < K_TOP && below + inclT >= K_TOP) {
        sh_below = below + exclT;
        sh_prefix = pref | ((unsigned long long)(unsigned)tid << shift);
      }
    }
    __syncthreads();

    if (r == 1) {
      // compact keys matching the 16-bit prefix to LDS; collect strictly-below keys to skey
      unsigned pref16 = (unsigned)(sh_prefix >> 48);
      for (int t = tid; t < N; t += nt) {
        unsigned long long k = kp[t];
        unsigned t16 = (unsigned)(k >> 48);
        if (t16 == pref16) {
          unsigned p = atomicAdd(&sh_scnt, 1u);
          if (p < SBUF_CAP) sbuf[p] = k;
        } else if (t16 < pref16) {
          unsigned p = atomicAdd(&sh_cnt, 1u);
          skey[p] = k;
        }
      }
      __syncthreads();
      scnt = sh_scnt;
      compacted = (scnt <= SBUF_CAP);
      __syncthreads();
    }
  }
  unsigned long long kth = sh_prefix | 0xFFFFull;

  // final collect into skey (exactly 512 total; top-48 bits unique)
  if (compacted) {
    for (int t = tid; t < (int)scnt; t += nt) {
      unsigned long long k = sbuf[t];
      if (k <= kth) { unsigned p = atomicAdd(&sh_cnt, 1u); skey[p] = k; }
    }
  } else {
    unsigned pref16 = (unsigned)(kth >> 48);
    for (int t = tid; t < N; t += nt) {
      unsigned long long k = kp[t];
      if ((unsigned)(k >> 48) == pref16 && k <= kth) {
        unsigned p = atomicAdd(&sh_cnt, 1u); skey[p] = k;
      }
    }
  }
  __syncthreads();

  // bitonic sort 512 ascending
  for (int kk = 2; kk <= K_TOP; kk <<= 1) {
    for (int j = kk >> 1; j > 0; j >>= 1) {
      if (tid < K_TOP) {
        int ixj = tid ^ j;
        if (ixj > tid) {
          bool up = ((tid & kk) == 0);
          unsigned long long A = skey[tid], B = skey[ixj];
          if ((A > B) == up) { skey[tid] = B; skey[ixj] = A; }
        }
      }
      __syncthreads();
    }
  }

  // epilogue: decode the 512 selected boxes to ws
  if (tid < K_TOP) {
    unsigned long long key = skey[tid];
    const float *boxp, *ancp;
    switch (l) {
      case 0:  boxp = box0; ancp = anc0; break;
      case 1:  boxp = box1; ancp = anc1; break;
      case 2:  boxp = box2; ancp = anc2; break;
      default: boxp = box3; ancp = anc3; break;
    }
    LvlC L = LVL[l];
    float imgf = (float)(*imgp);
    int idx = (int)((key >> 16) & 0xFFFFull);
    unsigned descu = (unsigned)(key >> 32);
    unsigned ascu  = ~descu;
    unsigned u = (ascu & 0x80000000u) ? (ascu & 0x7FFFFFFFu) : ~ascu;
    float x0, y0, x1, y1;
    decode_box(L, boxp, ancp, b, idx, imgf, x0, y0, x1, y1);
    int o = seg * K_TOP + tid;
    float4 bb; bb.x = x0; bb.y = y0; bb.z = x1; bb.w = y1;
    reinterpret_cast<float4*>(boxesWS)[o] = bb;
    scoresWS[o] = __uint_as_float(u);
    labelsWS[o] = (int)((key >> 8) & 0xFFull);
    validWS[o]  = (unsigned)(key & 1ull);
  }
}

// ---------------- Kernel 3: pairwise IoU>T suppression bitmasks (massively parallel) ----------------
__global__ __launch_bounds__(256) void mask_kernel(
    const float* __restrict__ boxesWS, unsigned long long* __restrict__ masks)
{
#pragma clang fp contract(off)
  int blk = (int)blockIdx.x;          // 512 blocks; 32 per segment
  int seg = blk >> 5;
  int wid = (int)threadIdx.x >> 6;    // 4 waves
  int lane = (int)threadIdx.x & 63;
  int waveInSeg = (blk & 31) * 4 + wid;   // 0..127, 4 rows each
  const float4* bb = reinterpret_cast<const float4*>(boxesWS) + seg * K_TOP;

  float4 bj[8]; float aj[8];
#pragma unroll
  for (int c = 0; c < 8; ++c) {
    bj[c] = bb[c * 64 + lane];
    aj[c] = (bj[c].z - bj[c].x) * (bj[c].w - bj[c].y);
  }
#pragma unroll
  for (int rr = 0; rr < 4; ++rr) {
    int r = waveInSeg * 4 + rr;
    float4 br = bb[r];
    float ar_ = (br.z - br.x) * (br.w - br.y);
    unsigned long long* mrow = masks + ((size_t)seg * K_TOP + r) * 8;
#pragma unroll
    for (int c = 0; c < 8; ++c) {
      float ltx = fmaxf(br.x, bj[c].x), lty = fmaxf(br.y, bj[c].y);
      float rbx = fminf(br.z, bj[c].z), rby = fminf(br.w, bj[c].w);
      float ww = fmaxf(rbx - ltx, 0.f), hh = fmaxf(rby - lty, 0.f);
      float inter = ww * hh;
      float iou = inter / (ar_ + aj[c] - inter + 1e-9f);
      unsigned long long bal = __ballot(iou > 0.5f);
      if (lane == 0) mrow[c] = bal;
    }
  }
}

// ---------------- Kernel 4: serial greedy scan over bitmasks + output write ----------------
__global__ __launch_bounds__(512) void scan_kernel(
    const unsigned long long* __restrict__ masks,
    const float* __restrict__ boxesWS, const float* __restrict__ scoresWS,
    const int* __restrict__ labelsWS, const unsigned* __restrict__ validWS,
    float* __restrict__ out)
{
  __shared__ unsigned long long sMask[K_TOP * 8];
  __shared__ unsigned sValid[K_TOP];
  __shared__ unsigned long long keepWords[8];

  int seg = (int)blockIdx.x;
  int tid = (int)threadIdx.x;
  const unsigned long long* mp = masks + (size_t)seg * K_TOP * 8;
#pragma unroll
  for (int k2 = 0; k2 < 8; ++k2) sMask[tid * 8 + k2] = mp[tid * 8 + k2];
  sValid[tid] = validWS[seg * K_TOP + tid];
  __syncthreads();

  if (tid < 8) {
    // lanes 0..7 each own one 64-bit word of the kept bitset
    unsigned long long kept = 0ull;
    for (int i = 0; i < K_TOP; ++i) {
      unsigned long long row = sMask[i * 8 + tid];
      unsigned long long confl = __ballot((row & kept) != 0ull);
      bool ok = (sValid[i] != 0u) && (confl == 0ull);
      kept |= (ok && (tid == (i >> 6))) ? (1ull << (i & 63)) : 0ull;
    }
    keepWords[tid] = kept;
  }
  __syncthreads();

  int o = seg * K_TOP + tid;
  bool keep = (keepWords[tid >> 6] >> (tid & 63)) & 1ull;
  float4 bx = reinterpret_cast<const float4*>(boxesWS)[o];
  float4 ob;
  ob.x = keep ? bx.x : 0.f;
  ob.y = keep ? bx.y : 0.f;
  ob.z = keep ? bx.z : 0.f;
  ob.w = keep ? bx.w : 0.f;
  reinterpret_cast<float4*>(out)[o] = ob;                   // boxes:  [0,      32768)
  out[32768 + o] = keep ? scoresWS[o] : 0.f;                // scores: [32768,  40960)
  out[40960 + o] = keep ? (float)(labelsWS[o] + 1) : 0.f;   // labels: [40960,  49152)
  out[49152 + o] = keep ? 1.f : 0.f;                        // keep:   [49152,  57344)
}

extern "C" void kernel_launch(void* const* d_in, const int* in_sizes, int n_in,
                              void* d_out, int out_size, void* d_ws, size_t ws_size,
                              hipStream_t stream)
{
  const float* cls0 = (const float*)d_in[0];
  const float* box0 = (const float*)d_in[1];
  const float* anc0 = (const float*)d_in[2];
  const float* cls1 = (const float*)d_in[3];
  const float* box1 = (const float*)d_in[4];
  const float* anc1 = (const float*)d_in[5];
  const float* cls2 = (const float*)d_in[6];
  const float* box2 = (const float*)d_in[7];
  const float* anc2 = (const float*)d_in[8];
  const float* cls3 = (const float*)d_in[9];
  const float* box3 = (const float*)d_in[10];
  const float* anc3 = (const float*)d_in[11];
  const int*   imgp = (const int*)d_in[12];

  // ws layout (bytes):
  char* ws = (char*)d_ws;
  unsigned long long* keys    = (unsigned long long*)(ws + 0);         // 261120*8 = 2,088,960
  unsigned long long* masks   = (unsigned long long*)(ws + 2088960);   // 16*512*8*8 = 524,288
  float*              boxesWS = (float*)(ws + 2613248);                // 16*512*4*4 = 131,072
  float*              scoresWS= (float*)(ws + 2744320);                // 32,768
  int*                labelsWS= (int*)(ws + 2777088);                  // 32,768
  unsigned*           validWS = (unsigned*)(ws + 2809856);             // 32,768
  unsigned*           ghist   = (unsigned*)(ws + 2842624);             // 16*256*4 = 16,384
  float* out = (float*)d_out;

  hipMemsetAsync(ghist, 0, 16 * 256 * sizeof(unsigned), stream);

  decode_kernel<<<1020, 256, 0, stream>>>(cls0, box0, anc0, cls1, box1, anc1,
                                          cls2, box2, anc2, cls3, box3, anc3,
                                          imgp, keys, ghist);
  select_kernel<<<16, 1024, 0, stream>>>(keys, ghist,
                                         box0, anc0, box1, anc1, box2, anc2, box3, anc3,
                                         imgp, boxesWS, scoresWS, labelsWS, validWS);
  mask_kernel<<<512, 256, 0, stream>>>(boxesWS, masks);
  scan_kernel<<<16, 512, 0, stream>>>(masks, boxesWS, scoresWS, labelsWS, validWS, out);
}